// Round 16
// baseline (42.618 us; speedup 1.0000x reference)
//
#include <hip/hip_runtime.h>
#include <hip/hip_bf16.h>
#include <math.h>

// B=4, N=512, T=288, L=128
#define NN 512
#define NT 288

// ---------------------------------------------------------------------------
// Kernel T: weight transpose (once per call, ~0.4 MB, L2-resident after).
// ---------------------------------------------------------------------------
__global__ __launch_bounds__(256) void kT(
    const float* __restrict__ W1, const float* __restrict__ W2,
    const float* __restrict__ Wp,
    float* __restrict__ Wt, float* __restrict__ Wpt)
{
    int g = blockIdx.x * 256 + threadIdx.x;
    if (g < 288 * 256) {
        int k = g >> 8, col = g & 255;
        Wt[g] = (col < 128) ? W1[col * 288 + k] : W2[(col - 128) * 288 + k];
    } else {
        int h = g - 288 * 256;          // 0 .. 32767
        int k = h >> 8, col = h & 255;
        Wpt[h] = (col < 128) ? Wp[col * 256 + k]
                             : Wp[(col - 128) * 256 + 128 + k];
    }
}

// ---------------------------------------------------------------------------
// Kernel P v5: 512 blocks x 256 threads, 4 rows/block.
// Thread = (c4 0..63, kq 0..3); wave == one K-quarter (uniform by construction).
// NEW vs R13/R15: (1) manual W double-buffer — step s+1's 4 dwordx4 issued
// before step s's FMAs (breaks load->FMA->load dependent chain independent
// of compiler back-edge scheduling); (2) 4-wave barriers (was 8) halve sync
// skew; 4 blocks/CU. LDS 25 KB. VGPR ~77 under __launch_bounds__(256,4).
// ---------------------------------------------------------------------------
__global__ __launch_bounds__(256, 4) void kP(
    const float* __restrict__ x,    // [2048][288]
    const float* __restrict__ Wt,   // [288][256]
    const float* __restrict__ b1,   // [128]
    const float* __restrict__ b2,   // [128]
    const float* __restrict__ Wpt,  // [128][256]
    const float* __restrict__ bp,   // [128]
    const float* __restrict__ Wb,   // [128]
    const float* __restrict__ bb,   // [1]
    float* __restrict__ S12,        // ws [2048][256]
    float* __restrict__ Aarr,       // ws [2048]
    float* __restrict__ Carr)       // ws [2048]
{
    __shared__ __align__(16) float xs[4 * NT];      // 4.6 KB
    __shared__ __align__(16) float x12s[4 * 256];   // 4 KB
    __shared__ __align__(16) float ph[3 * 1024];    // 12 KB
    __shared__ __align__(16) float s12s[4 * 260];   // 4.2 KB

    const int t   = threadIdx.x;
    const int bn0 = blockIdx.x * 4;
    const int c4  = t & 63;         // col quad
    const int kq  = t >> 6;         // K-quarter == wave index

    // stage 4 x-rows (288 float4)
    for (int q = 0; q < 2; ++q) {
        int idx = q * 256 + t;
        if (idx < 288) {
            int row = idx / 72, cc = idx % 72;
            *(float4*)&xs[row * NT + cc * 4] =
                *(const float4*)&x[(size_t)(bn0 + row) * NT + cc * 4];
        }
    }
    __syncthreads();

    // ---- G1: 4 cols x 4 rows, K=288 split 4 x 72 (18 steps), W dbuf ----
    float acc[4][4];
#pragma unroll
    for (int n = 0; n < 4; ++n)
#pragma unroll
        for (int c = 0; c < 4; ++c) acc[n][c] = 0.0f;

    const int kb1 = kq * 72;
    const float* wcol = Wt + (size_t)kb1 * 256 + c4 * 4;

    float4 cw0 = *(const float4*)&wcol[0];
    float4 cw1 = *(const float4*)&wcol[256];
    float4 cw2 = *(const float4*)&wcol[512];
    float4 cw3 = *(const float4*)&wcol[768];

#pragma unroll 1
    for (int s = 0; s < 18; ++s) {
        float4 nw0, nw1, nw2, nw3;
        if (s < 17) {                       // prefetch next step's W
            const float* wn = wcol + (size_t)(s + 1) * 1024;
            nw0 = *(const float4*)&wn[0];
            nw1 = *(const float4*)&wn[256];
            nw2 = *(const float4*)&wn[512];
            nw3 = *(const float4*)&wn[768];
        }
        const int k0 = kb1 + s * 4;
        const float* w0p = (const float*)&cw0;
        const float* w1p = (const float*)&cw1;
        const float* w2p = (const float*)&cw2;
        const float* w3p = (const float*)&cw3;
#pragma unroll
        for (int n = 0; n < 4; ++n) {
            float4 xv = *(const float4*)&xs[n * NT + k0];   // wave-broadcast
#pragma unroll
            for (int c = 0; c < 4; ++c) {
                acc[n][c] = fmaf(xv.x, w0p[c], acc[n][c]);
                acc[n][c] = fmaf(xv.y, w1p[c], acc[n][c]);
                acc[n][c] = fmaf(xv.z, w2p[c], acc[n][c]);
                acc[n][c] = fmaf(xv.w, w3p[c], acc[n][c]);
            }
        }
        if (s < 17) { cw0 = nw0; cw1 = nw1; cw2 = nw2; cw3 = nw3; }
    }

    // kq-reduce via ph
    if (kq) {
#pragma unroll
        for (int n = 0; n < 4; ++n) {
            float4 v = {acc[n][0], acc[n][1], acc[n][2], acc[n][3]};
            *(float4*)&ph[(kq - 1) * 1024 + n * 256 + c4 * 4] = v;
        }
    }
    __syncthreads();
    if (!kq) {
        float4 bias4 = (c4 < 32) ? *(const float4*)&b1[c4 * 4]
                                 : *(const float4*)&b2[(c4 - 32) * 4];
        const float* bp4 = (const float*)&bias4;
#pragma unroll
        for (int n = 0; n < 4; ++n) {
            float s0 = acc[n][0], s1 = acc[n][1], s2 = acc[n][2], s3 = acc[n][3];
#pragma unroll
            for (int p = 0; p < 3; ++p) {
                float4 v = *(const float4*)&ph[p * 1024 + n * 256 + c4 * 4];
                s0 += v.x; s1 += v.y; s2 += v.z; s3 += v.w;
            }
            float sv[4] = {s0, s1, s2, s3};
            float4 r;
            float* rp = (float*)&r;
#pragma unroll
            for (int c = 0; c < 4; ++c) {
                float v = sv[c] + bp4[c];
                rp[c] = fmaxf(v, 0.2f * v);     // leaky
            }
            *(float4*)&x12s[n * 256 + c4 * 4] = r;
        }
    }
    __syncthreads();

    // ---- G2: 4 cols x 4 rows, K=128 split 4 x 32 (8 steps), W dbuf ----
    float acc2[4][4];
#pragma unroll
    for (int n = 0; n < 4; ++n)
#pragma unroll
        for (int c = 0; c < 4; ++c) acc2[n][c] = 0.0f;

    const int koff = (c4 < 32) ? 0 : 128;
    const int kb2 = kq * 32;
    const float* wpcol = Wpt + (size_t)kb2 * 256 + c4 * 4;

    float4 dw0 = *(const float4*)&wpcol[0];
    float4 dw1 = *(const float4*)&wpcol[256];
    float4 dw2 = *(const float4*)&wpcol[512];
    float4 dw3 = *(const float4*)&wpcol[768];

#pragma unroll 1
    for (int s = 0; s < 8; ++s) {
        float4 nw0, nw1, nw2, nw3;
        if (s < 7) {
            const float* wn = wpcol + (size_t)(s + 1) * 1024;
            nw0 = *(const float4*)&wn[0];
            nw1 = *(const float4*)&wn[256];
            nw2 = *(const float4*)&wn[512];
            nw3 = *(const float4*)&wn[768];
        }
        const int k0 = kb2 + s * 4;
        const float* w0p = (const float*)&dw0;
        const float* w1p = (const float*)&dw1;
        const float* w2p = (const float*)&dw2;
        const float* w3p = (const float*)&dw3;
#pragma unroll
        for (int n = 0; n < 4; ++n) {
            float4 xv = *(const float4*)&x12s[n * 256 + koff + k0];  // 2-grp bcast
#pragma unroll
            for (int c = 0; c < 4; ++c) {
                acc2[n][c] = fmaf(xv.x, w0p[c], acc2[n][c]);
                acc2[n][c] = fmaf(xv.y, w1p[c], acc2[n][c]);
                acc2[n][c] = fmaf(xv.z, w2p[c], acc2[n][c]);
                acc2[n][c] = fmaf(xv.w, w3p[c], acc2[n][c]);
            }
        }
        if (s < 7) { dw0 = nw0; dw1 = nw1; dw2 = nw2; dw3 = nw3; }
    }

    if (kq) {
#pragma unroll
        for (int n = 0; n < 4; ++n) {
            float4 v = {acc2[n][0], acc2[n][1], acc2[n][2], acc2[n][3]};
            *(float4*)&ph[(kq - 1) * 1024 + n * 256 + c4 * 4] = v;
        }
    }
    __syncthreads();
    if (!kq) {
        float4 bias4;
        if (c4 < 32) bias4 = *(const float4*)&bp[c4 * 4];
        else         bias4 = make_float4(0.f, 0.f, 0.f, 0.f);
        const float* bp4 = (const float*)&bias4;
#pragma unroll
        for (int n = 0; n < 4; ++n) {
            float s0 = acc2[n][0], s1 = acc2[n][1], s2 = acc2[n][2], s3 = acc2[n][3];
#pragma unroll
            for (int p = 0; p < 3; ++p) {
                float4 v = *(const float4*)&ph[p * 1024 + n * 256 + c4 * 4];
                s0 += v.x; s1 += v.y; s2 += v.z; s3 += v.w;
            }
            float sv[4] = {s0, s1, s2, s3};
            float4 r;
            float* rp = (float*)&r;
#pragma unroll
            for (int c = 0; c < 4; ++c) rp[c] = sv[c] + bp4[c];
            *(float4*)&S12[(size_t)(bn0 + n) * 256 + c4 * 4] = r;
            *(float4*)&s12s[n * 260 + c4 * 4] = r;
        }
    }
    __syncthreads();

    // ---- per-row dots with Wb: 8 dots x 32 lanes (all 256 threads) ----
    {
        int lane32 = t & 31;
        int n = (t >> 5) & 3;
        int isC = t >> 7;
        int base = isC ? 128 : 0;
        float sum = 0.0f;
#pragma unroll
        for (int s = 0; s < 4; ++s) {
            int j = lane32 + s * 32;
            sum = fmaf(s12s[n * 260 + base + j], Wb[j], sum);
        }
#pragma unroll
        for (int m = 16; m >= 1; m >>= 1)
            sum += __shfl_xor(sum, m, 32);
        if (lane32 == 0) {
            if (isC) Carr[bn0 + n] = 0.6f * sum;
            else     Aarr[bn0 + n] = 0.6f * sum + bb[0];
        }
    }
}

// ---------------------------------------------------------------------------
// Kernel Q: R13/R7-verified fused kernel (4x4 tile, 12.5 us). Unchanged.
// ---------------------------------------------------------------------------
__global__ __launch_bounds__(512) void kQ(
    const float* __restrict__ S12,   // [2048][256]
    const float* __restrict__ Aarr,  // [2048]
    const float* __restrict__ Carr,  // [2048]
    const float* __restrict__ Wb,    // [128]
    const float* __restrict__ noise, // [512][512]
    float* __restrict__ out)         // [512][512]
{
    __shared__ __align__(16) float smem[32768];   // 128 KB
    float* S1t = smem;             // [4][128][32]
    float* S2t = smem + 16384;     // [4][128][32]

    const int t = threadIdx.x;
    const int bx = blockIdx.x, by = blockIdx.y;

#pragma unroll
    for (int q = 0; q < 16; ++q) {
        int task = q * 512 + t;
        int isS2 = task >> 12;
        int r    = task & 4095;
        int bz   = r >> 10;
        int row  = (r >> 5) & 31;
        int c4   = r & 31;
        size_t src = (size_t)(bz * NN + (isS2 ? by : bx) * 32 + row) * 256
                     + (isS2 ? 128 : 0) + c4 * 4;
        float4 v = *(const float4*)&S12[src];
        float* dst = (isS2 ? S2t : S1t) + bz * 4096;
        int rw = row ^ ((c4 & 7) << 2);
        dst[(c4 * 4 + 0) * 32 + rw] = v.x;
        dst[(c4 * 4 + 1) * 32 + rw] = v.y;
        dst[(c4 * 4 + 2) * 32 + rw] = v.z;
        dst[(c4 * 4 + 3) * 32 + rw] = v.w;
    }
    __syncthreads();

    const int lh = t >> 8;
    const int bz = (t >> 6) & 3;
    const int s  = t & 63;
    const int i0 = (s >> 3) << 2, j0 = (s & 7) << 2;

    const float* S1b = S1t + bz * 4096 + lh * 64 * 32;
    const float* S2b = S2t + bz * 4096 + lh * 64 * 32;
    const float* wbp = Wb + lh * 64;

    float accv[16];
#pragma unroll
    for (int k = 0; k < 16; ++k) accv[k] = 0.0f;

    for (int l4 = 0; l4 < 16; ++l4) {
        const int sw = (l4 & 7) << 2;
        const int lrow = l4 * 4 * 32;
        float4 wv = *(const float4*)&wbp[l4 * 4];
        const float wl[4] = {wv.x, wv.y, wv.z, wv.w};
#pragma unroll
        for (int d = 0; d < 4; ++d) {
            float4 a = *(const float4*)&S1b[lrow + d * 32 + (i0 ^ sw)];
            float4 b = *(const float4*)&S2b[lrow + d * 32 + (j0 ^ sw)];
            float w = wl[d];
            float ai[4] = {a.x, a.y, a.z, a.w};
            float bj[4] = {b.x, b.y, b.z, b.w};
#pragma unroll
            for (int ii = 0; ii < 4; ++ii)
#pragma unroll
                for (int jj = 0; jj < 4; ++jj) {
                    float tv = ai[ii] + bj[jj];
                    accv[ii * 4 + jj] = fmaf(fabsf(tv), w, accv[ii * 4 + jj]);
                }
        }
    }

    float* red = smem;
    const int tid2 = t & 255;
    __syncthreads();
    if (lh) {
#pragma unroll
        for (int q = 0; q < 4; ++q) {
            float4 v = {accv[4 * q], accv[4 * q + 1], accv[4 * q + 2], accv[4 * q + 3]};
            *(float4*)&red[q * 1024 + tid2 * 4] = v;
        }
    }
    __syncthreads();

    float sig[16];
    if (!lh) {
#pragma unroll
        for (int q = 0; q < 4; ++q) {
            float4 v = *(const float4*)&red[q * 1024 + tid2 * 4];
            accv[4 * q]     += v.x;
            accv[4 * q + 1] += v.y;
            accv[4 * q + 2] += v.z;
            accv[4 * q + 3] += v.w;
        }
        float Av[4], Cv[4];
#pragma unroll
        for (int ii = 0; ii < 4; ++ii) Av[ii] = Aarr[bz * NN + bx * 32 + i0 + ii];
#pragma unroll
        for (int jj = 0; jj < 4; ++jj) Cv[jj] = Carr[bz * NN + by * 32 + j0 + jj];
#pragma unroll
        for (int ii = 0; ii < 4; ++ii)
#pragma unroll
            for (int jj = 0; jj < 4; ++jj) {
                float lg = Av[ii] + Cv[jj] + 0.4f * accv[ii * 4 + jj];
                sig[ii * 4 + jj] = 1.0f / (1.0f + expf(-lg));
            }
        float* redB = smem + 4096;
        if (bz) {
#pragma unroll
            for (int q = 0; q < 4; ++q) {
                float4 v = {sig[4 * q], sig[4 * q + 1], sig[4 * q + 2], sig[4 * q + 3]};
                *(float4*)&redB[(bz - 1) * 1024 + q * 256 + s * 4] = v;
            }
        }
    }
    __syncthreads();

    float* redB = smem + 4096;
    float* redP = smem + 7168;
    if (t < 64) {                          // lh=0, bz=0, s=t
#pragma unroll
        for (int bzz = 0; bzz < 3; ++bzz)
#pragma unroll
            for (int q = 0; q < 4; ++q) {
                float4 v = *(const float4*)&redB[bzz * 1024 + q * 256 + t * 4];
                sig[4 * q]     += v.x;
                sig[4 * q + 1] += v.y;
                sig[4 * q + 2] += v.z;
                sig[4 * q + 3] += v.w;
            }
#pragma unroll
        for (int q = 0; q < 4; ++q) {
            float4 v = {sig[4 * q], sig[4 * q + 1], sig[4 * q + 2], sig[4 * q + 3]};
            *(float4*)&redP[t * 16 + q * 4] = v;
        }
    }
    __syncthreads();

    if (t < 256) {
        int i   = t >> 3;
        int j0f = (t & 7) * 4;
        int sP  = (t >> 5) * 8 + (t & 7);
        int k0  = ((t >> 3) & 3) * 4;
        float4 pv4 = *(const float4*)&redP[sP * 16 + k0];
        float pv[4] = {pv4.x, pv4.y, pv4.z, pv4.w};

        int gi = bx * 32 + i;
        size_t base = (size_t)gi * NN + by * 32 + j0f;
        float4 nz = *(const float4*)&noise[base];
        float nv[4] = {nz.x, nz.y, nz.z, nz.w};

        float4 o;
        float* op = (float*)&o;
#pragma unroll
        for (int c = 0; c < 4; ++c) {
            float p = 0.25f * pv[c];
            int gj = by * 32 + j0f + c;
            if (gj == gi) p = 0.0f;
            float lp = logf(p + 1e-10f) - log1pf(-p + 1e-10f);
            lp = fminf(fmaxf(lp, -10.0f), 10.0f);
            float lgs = logf(nv[c]) - log1pf(-nv[c]);
            op[c] = 1.0f / (1.0f + expf(-(lp + lgs) * 5.0f));
        }
        *(float4*)&out[base] = o;
    }
}

// ---------------------------------------------------------------------------
extern "C" void kernel_launch(void* const* d_in, const int* in_sizes, int n_in,
                              void* d_out, int out_size, void* d_ws, size_t ws_size,
                              hipStream_t stream) {
    const float* x     = (const float*)d_in[0];
    const float* W1    = (const float*)d_in[1];
    const float* b1    = (const float*)d_in[2];
    const float* W2    = (const float*)d_in[3];
    const float* b2    = (const float*)d_in[4];
    const float* Wp    = (const float*)d_in[5];
    const float* bp    = (const float*)d_in[6];
    const float* Wb    = (const float*)d_in[7];
    const float* bb    = (const float*)d_in[8];
    const float* noise = (const float*)d_in[9];

    float* ws   = (float*)d_ws;
    float* S12  = ws;                   // 524288 floats
    float* Aarr = ws + 524288;          // 2048
    float* Carr = Aarr + 2048;          // 2048
    float* Wt   = Carr + 2048;          // 73728
    float* Wpt  = Wt + 73728;           // 32768

    kT<<<416, 256, 0, stream>>>(W1, W2, Wp, Wt, Wpt);
    kP<<<512, 256, 0, stream>>>(x, Wt, b1, b2, Wpt, bp, Wb, bb,
                                S12, Aarr, Carr);
    kQ<<<dim3(16, 16), 512, 0, stream>>>(S12, Aarr, Carr, Wb, noise,
                                         (float*)d_out);
}

// Round 17
// 38.263 us; speedup vs baseline: 1.1138x; 1.1138x over previous
//
#include <hip/hip_runtime.h>
#include <hip/hip_bf16.h>
#include <math.h>

// B=4, N=512, T=288, L=128
#define NN 512
#define NT 288

// ---------------------------------------------------------------------------
// Kernel T: weight transpose (once per call, ~0.4 MB, L2-resident after).
// ---------------------------------------------------------------------------
__global__ __launch_bounds__(256) void kT(
    const float* __restrict__ W1, const float* __restrict__ W2,
    const float* __restrict__ Wp,
    float* __restrict__ Wt, float* __restrict__ Wpt)
{
    int g = blockIdx.x * 256 + threadIdx.x;
    if (g < 288 * 256) {
        int k = g >> 8, col = g & 255;
        Wt[g] = (col < 128) ? W1[col * 288 + k] : W2[(col - 128) * 288 + k];
    } else {
        int h = g - 288 * 256;          // 0 .. 32767
        int k = h >> 8, col = h & 255;
        Wpt[h] = (col < 128) ? Wp[col * 256 + k]
                             : Wp[(col - 128) * 256 + 128 + k];
    }
}

// ---------------------------------------------------------------------------
// Kernel P (R13-verified best): 256 blocks x 512 threads = (c4 0..63,
// khe 0..7); thread computes 4 cols x 8 rows over K/8. Per wave: G1 72 +
// G2 32 broadcast ds_read_b128 (4x fewer than R6); W loads coalesced from
// transposed Wt/Wpt. K-partials reduced via 56KB LDS ph buffer.
// ---------------------------------------------------------------------------
__global__ __launch_bounds__(512) void kP(
    const float* __restrict__ x,    // [2048][288]
    const float* __restrict__ Wt,   // [288][256]
    const float* __restrict__ b1,   // [128]
    const float* __restrict__ b2,   // [128]
    const float* __restrict__ Wpt,  // [128][256]
    const float* __restrict__ bp,   // [128]
    const float* __restrict__ Wb,   // [128]
    const float* __restrict__ bb,   // [1]
    float* __restrict__ S12,        // ws [2048][256]
    float* __restrict__ Aarr,       // ws [2048]
    float* __restrict__ Carr)       // ws [2048]
{
    __shared__ __align__(16) float xs[8 * NT];      // 9.2 KB
    __shared__ __align__(16) float x12s[8 * 256];   // 8 KB
    __shared__ __align__(16) float ph[7 * 2048];    // 57.3 KB
    __shared__ __align__(16) float s12s[8 * 260];   // 8.3 KB

    const int t   = threadIdx.x;
    const int bn0 = blockIdx.x * 8;
    const int c4  = t & 63;
    const int khe = t >> 6;

    for (int q = 0; q < 2; ++q) {
        int idx = q * 512 + t;
        if (idx < 576) {
            int row = idx / 72, cc = idx % 72;
            *(float4*)&xs[row * NT + cc * 4] =
                *(const float4*)&x[(size_t)(bn0 + row) * NT + cc * 4];
        }
    }
    __syncthreads();

    float acc[8][4];
#pragma unroll
    for (int n = 0; n < 8; ++n)
#pragma unroll
        for (int c = 0; c < 4; ++c) acc[n][c] = 0.0f;

    const int kbase1 = khe * 36;
#pragma unroll 2
    for (int k4 = 0; k4 < 9; ++k4) {
        const int k0 = kbase1 + k4 * 4;
        float4 w0 = *(const float4*)&Wt[(size_t)(k0 + 0) * 256 + c4 * 4];
        float4 w1 = *(const float4*)&Wt[(size_t)(k0 + 1) * 256 + c4 * 4];
        float4 w2 = *(const float4*)&Wt[(size_t)(k0 + 2) * 256 + c4 * 4];
        float4 w3 = *(const float4*)&Wt[(size_t)(k0 + 3) * 256 + c4 * 4];
        const float* w0p = (const float*)&w0;
        const float* w1p = (const float*)&w1;
        const float* w2p = (const float*)&w2;
        const float* w3p = (const float*)&w3;
#pragma unroll
        for (int n = 0; n < 8; ++n) {
            float4 xv = *(const float4*)&xs[n * NT + k0];
#pragma unroll
            for (int c = 0; c < 4; ++c) {
                acc[n][c] = fmaf(xv.x, w0p[c], acc[n][c]);
                acc[n][c] = fmaf(xv.y, w1p[c], acc[n][c]);
                acc[n][c] = fmaf(xv.z, w2p[c], acc[n][c]);
                acc[n][c] = fmaf(xv.w, w3p[c], acc[n][c]);
            }
        }
    }

    if (khe) {
#pragma unroll
        for (int n = 0; n < 8; ++n) {
            float4 v = {acc[n][0], acc[n][1], acc[n][2], acc[n][3]};
            *(float4*)&ph[(khe - 1) * 2048 + n * 256 + c4 * 4] = v;
        }
    }
    __syncthreads();
    if (!khe) {
        float4 bias4 = (c4 < 32) ? *(const float4*)&b1[c4 * 4]
                                 : *(const float4*)&b2[(c4 - 32) * 4];
        const float* bp4 = (const float*)&bias4;
#pragma unroll
        for (int n = 0; n < 8; ++n) {
            float s0 = acc[n][0], s1 = acc[n][1], s2 = acc[n][2], s3 = acc[n][3];
#pragma unroll
            for (int p = 0; p < 7; ++p) {
                float4 v = *(const float4*)&ph[p * 2048 + n * 256 + c4 * 4];
                s0 += v.x; s1 += v.y; s2 += v.z; s3 += v.w;
            }
            float4 r;
            float* rp = (float*)&r;
            float sv[4] = {s0, s1, s2, s3};
#pragma unroll
            for (int c = 0; c < 4; ++c) {
                float v = sv[c] + bp4[c];
                rp[c] = fmaxf(v, 0.2f * v);
            }
            *(float4*)&x12s[n * 256 + c4 * 4] = r;
        }
    }
    __syncthreads();

    float acc2[8][4];
#pragma unroll
    for (int n = 0; n < 8; ++n)
#pragma unroll
        for (int c = 0; c < 4; ++c) acc2[n][c] = 0.0f;

    const int koff = (c4 < 32) ? 0 : 128;
    const int kbase2 = khe * 16;
#pragma unroll 2
    for (int k4 = 0; k4 < 4; ++k4) {
        const int k0 = kbase2 + k4 * 4;
        float4 w0 = *(const float4*)&Wpt[(size_t)(k0 + 0) * 256 + c4 * 4];
        float4 w1 = *(const float4*)&Wpt[(size_t)(k0 + 1) * 256 + c4 * 4];
        float4 w2 = *(const float4*)&Wpt[(size_t)(k0 + 2) * 256 + c4 * 4];
        float4 w3 = *(const float4*)&Wpt[(size_t)(k0 + 3) * 256 + c4 * 4];
        const float* w0p = (const float*)&w0;
        const float* w1p = (const float*)&w1;
        const float* w2p = (const float*)&w2;
        const float* w3p = (const float*)&w3;
#pragma unroll
        for (int n = 0; n < 8; ++n) {
            float4 xv = *(const float4*)&x12s[n * 256 + koff + k0];
#pragma unroll
            for (int c = 0; c < 4; ++c) {
                acc2[n][c] = fmaf(xv.x, w0p[c], acc2[n][c]);
                acc2[n][c] = fmaf(xv.y, w1p[c], acc2[n][c]);
                acc2[n][c] = fmaf(xv.z, w2p[c], acc2[n][c]);
                acc2[n][c] = fmaf(xv.w, w3p[c], acc2[n][c]);
            }
        }
    }

    if (khe) {
#pragma unroll
        for (int n = 0; n < 8; ++n) {
            float4 v = {acc2[n][0], acc2[n][1], acc2[n][2], acc2[n][3]};
            *(float4*)&ph[(khe - 1) * 2048 + n * 256 + c4 * 4] = v;
        }
    }
    __syncthreads();
    if (!khe) {
        float4 bias4;
        if (c4 < 32) bias4 = *(const float4*)&bp[c4 * 4];
        else         bias4 = make_float4(0.f, 0.f, 0.f, 0.f);
        const float* bp4 = (const float*)&bias4;
#pragma unroll
        for (int n = 0; n < 8; ++n) {
            float s0 = acc2[n][0], s1 = acc2[n][1], s2 = acc2[n][2], s3 = acc2[n][3];
#pragma unroll
            for (int p = 0; p < 7; ++p) {
                float4 v = *(const float4*)&ph[p * 2048 + n * 256 + c4 * 4];
                s0 += v.x; s1 += v.y; s2 += v.z; s3 += v.w;
            }
            float sv[4] = {s0, s1, s2, s3};
            float4 r;
            float* rp = (float*)&r;
#pragma unroll
            for (int c = 0; c < 4; ++c) rp[c] = sv[c] + bp4[c];
            *(float4*)&S12[(size_t)(bn0 + n) * 256 + c4 * 4] = r;
            *(float4*)&s12s[n * 260 + c4 * 4] = r;
        }
    }
    __syncthreads();

    {
        int lane32 = t & 31;
        int n = (t >> 5) & 7;
        int isC = t >> 8;
        int base = isC ? 128 : 0;
        float sum = 0.0f;
#pragma unroll
        for (int s = 0; s < 4; ++s) {
            int j = lane32 + s * 32;
            sum = fmaf(s12s[n * 260 + base + j], Wb[j], sum);
        }
#pragma unroll
        for (int m = 16; m >= 1; m >>= 1)
            sum += __shfl_xor(sum, m, 32);
        if (lane32 == 0) {
            if (isC) Carr[bn0 + n] = 0.6f * sum;
            else     Aarr[bn0 + n] = 0.6f * sum + bb[0];
        }
    }
}

// ---------------------------------------------------------------------------
// Kernel Q: R7/R13-verified fused pairwise + mean-over-b + phase F.
// grid (16,16) = 32x32 tile, all 4 b-slices per block, 512 threads.
// ---------------------------------------------------------------------------
__global__ __launch_bounds__(512) void kQ(
    const float* __restrict__ S12,   // [2048][256]
    const float* __restrict__ Aarr,  // [2048]
    const float* __restrict__ Carr,  // [2048]
    const float* __restrict__ Wb,    // [128]
    const float* __restrict__ noise, // [512][512]
    float* __restrict__ out)         // [512][512]
{
    __shared__ __align__(16) float smem[32768];   // 128 KB
    float* S1t = smem;             // [4][128][32]
    float* S2t = smem + 16384;     // [4][128][32]

    const int t = threadIdx.x;
    const int bx = blockIdx.x, by = blockIdx.y;

#pragma unroll
    for (int q = 0; q < 16; ++q) {
        int task = q * 512 + t;
        int isS2 = task >> 12;
        int r    = task & 4095;
        int bz   = r >> 10;
        int row  = (r >> 5) & 31;
        int c4   = r & 31;
        size_t src = (size_t)(bz * NN + (isS2 ? by : bx) * 32 + row) * 256
                     + (isS2 ? 128 : 0) + c4 * 4;
        float4 v = *(const float4*)&S12[src];
        float* dst = (isS2 ? S2t : S1t) + bz * 4096;
        int rw = row ^ ((c4 & 7) << 2);
        dst[(c4 * 4 + 0) * 32 + rw] = v.x;
        dst[(c4 * 4 + 1) * 32 + rw] = v.y;
        dst[(c4 * 4 + 2) * 32 + rw] = v.z;
        dst[(c4 * 4 + 3) * 32 + rw] = v.w;
    }
    __syncthreads();

    const int lh = t >> 8;
    const int bz = (t >> 6) & 3;
    const int s  = t & 63;
    const int i0 = (s >> 3) << 2, j0 = (s & 7) << 2;

    const float* S1b = S1t + bz * 4096 + lh * 64 * 32;
    const float* S2b = S2t + bz * 4096 + lh * 64 * 32;
    const float* wbp = Wb + lh * 64;

    float accv[16];
#pragma unroll
    for (int k = 0; k < 16; ++k) accv[k] = 0.0f;

    for (int l4 = 0; l4 < 16; ++l4) {
        const int sw = (l4 & 7) << 2;
        const int lrow = l4 * 4 * 32;
        float4 wv = *(const float4*)&wbp[l4 * 4];
        const float wl[4] = {wv.x, wv.y, wv.z, wv.w};
#pragma unroll
        for (int d = 0; d < 4; ++d) {
            float4 a = *(const float4*)&S1b[lrow + d * 32 + (i0 ^ sw)];
            float4 b = *(const float4*)&S2b[lrow + d * 32 + (j0 ^ sw)];
            float w = wl[d];
            float ai[4] = {a.x, a.y, a.z, a.w};
            float bj[4] = {b.x, b.y, b.z, b.w};
#pragma unroll
            for (int ii = 0; ii < 4; ++ii)
#pragma unroll
                for (int jj = 0; jj < 4; ++jj) {
                    float tv = ai[ii] + bj[jj];
                    accv[ii * 4 + jj] = fmaf(fabsf(tv), w, accv[ii * 4 + jj]);
                }
        }
    }

    float* red = smem;
    const int tid2 = t & 255;
    __syncthreads();
    if (lh) {
#pragma unroll
        for (int q = 0; q < 4; ++q) {
            float4 v = {accv[4 * q], accv[4 * q + 1], accv[4 * q + 2], accv[4 * q + 3]};
            *(float4*)&red[q * 1024 + tid2 * 4] = v;
        }
    }
    __syncthreads();

    float sig[16];
    if (!lh) {
#pragma unroll
        for (int q = 0; q < 4; ++q) {
            float4 v = *(const float4*)&red[q * 1024 + tid2 * 4];
            accv[4 * q]     += v.x;
            accv[4 * q + 1] += v.y;
            accv[4 * q + 2] += v.z;
            accv[4 * q + 3] += v.w;
        }
        float Av[4], Cv[4];
#pragma unroll
        for (int ii = 0; ii < 4; ++ii) Av[ii] = Aarr[bz * NN + bx * 32 + i0 + ii];
#pragma unroll
        for (int jj = 0; jj < 4; ++jj) Cv[jj] = Carr[bz * NN + by * 32 + j0 + jj];
#pragma unroll
        for (int ii = 0; ii < 4; ++ii)
#pragma unroll
            for (int jj = 0; jj < 4; ++jj) {
                float lg = Av[ii] + Cv[jj] + 0.4f * accv[ii * 4 + jj];
                sig[ii * 4 + jj] = 1.0f / (1.0f + expf(-lg));
            }
        float* redB = smem + 4096;
        if (bz) {
#pragma unroll
            for (int q = 0; q < 4; ++q) {
                float4 v = {sig[4 * q], sig[4 * q + 1], sig[4 * q + 2], sig[4 * q + 3]};
                *(float4*)&redB[(bz - 1) * 1024 + q * 256 + s * 4] = v;
            }
        }
    }
    __syncthreads();

    float* redB = smem + 4096;
    float* redP = smem + 7168;
    if (t < 64) {                          // lh=0, bz=0, s=t
#pragma unroll
        for (int bzz = 0; bzz < 3; ++bzz)
#pragma unroll
            for (int q = 0; q < 4; ++q) {
                float4 v = *(const float4*)&redB[bzz * 1024 + q * 256 + t * 4];
                sig[4 * q]     += v.x;
                sig[4 * q + 1] += v.y;
                sig[4 * q + 2] += v.z;
                sig[4 * q + 3] += v.w;
            }
#pragma unroll
        for (int q = 0; q < 4; ++q) {
            float4 v = {sig[4 * q], sig[4 * q + 1], sig[4 * q + 2], sig[4 * q + 3]};
            *(float4*)&redP[t * 16 + q * 4] = v;
        }
    }
    __syncthreads();

    if (t < 256) {
        int i   = t >> 3;
        int j0f = (t & 7) * 4;
        int sP  = (t >> 5) * 8 + (t & 7);
        int k0  = ((t >> 3) & 3) * 4;
        float4 pv4 = *(const float4*)&redP[sP * 16 + k0];
        float pv[4] = {pv4.x, pv4.y, pv4.z, pv4.w};

        int gi = bx * 32 + i;
        size_t base = (size_t)gi * NN + by * 32 + j0f;
        float4 nz = *(const float4*)&noise[base];
        float nv[4] = {nz.x, nz.y, nz.z, nz.w};

        float4 o;
        float* op = (float*)&o;
#pragma unroll
        for (int c = 0; c < 4; ++c) {
            float p = 0.25f * pv[c];
            int gj = by * 32 + j0f + c;
            if (gj == gi) p = 0.0f;
            float lp = logf(p + 1e-10f) - log1pf(-p + 1e-10f);
            lp = fminf(fmaxf(lp, -10.0f), 10.0f);
            float lgs = logf(nv[c]) - log1pf(-nv[c]);
            op[c] = 1.0f / (1.0f + expf(-(lp + lgs) * 5.0f));
        }
        *(float4*)&out[base] = o;
    }
}

// ---------------------------------------------------------------------------
extern "C" void kernel_launch(void* const* d_in, const int* in_sizes, int n_in,
                              void* d_out, int out_size, void* d_ws, size_t ws_size,
                              hipStream_t stream) {
    const float* x     = (const float*)d_in[0];
    const float* W1    = (const float*)d_in[1];
    const float* b1    = (const float*)d_in[2];
    const float* W2    = (const float*)d_in[3];
    const float* b2    = (const float*)d_in[4];
    const float* Wp    = (const float*)d_in[5];
    const float* bp    = (const float*)d_in[6];
    const float* Wb    = (const float*)d_in[7];
    const float* bb    = (const float*)d_in[8];
    const float* noise = (const float*)d_in[9];

    float* ws   = (float*)d_ws;
    float* S12  = ws;                   // 524288 floats
    float* Aarr = ws + 524288;          // 2048
    float* Carr = Aarr + 2048;          // 2048
    float* Wt   = Carr + 2048;          // 73728
    float* Wpt  = Wt + 73728;           // 32768

    kT<<<416, 256, 0, stream>>>(W1, W2, Wp, Wt, Wpt);
    kP<<<256, 512, 0, stream>>>(x, Wt, b1, b2, Wpt, bp, Wb, bb,
                                S12, Aarr, Carr);
    kQ<<<dim3(16, 16), 512, 0, stream>>>(S12, Aarr, Carr, Wb, noise,
                                         (float*)d_out);
}